// Round 1
// baseline (253.870 us; speedup 1.0000x reference)
//
#include <hip/hip_runtime.h>
#include <math.h>

#define NATOMS 2048
#define DIM 64

// Each wave handles 4 pairs per loop iteration:
//   group g = lane>>4 -> pair p0+g
//   q = lane&15 -> this lane owns basis/output dims d0 = q*4 .. q*4+3
// t[m] = sum_d basis_d * w1[d][m]  (reduced over the 16 lanes of the group)
// out[o] = sum_m t[m] * w2[m][o]
__global__ __launch_bounds__(256) void bessel_rbf_kernel(
    const float* __restrict__ atoms,
    const float* __restrict__ w1,   // (64,4)
    const float* __restrict__ w2,   // (4,64)
    float* __restrict__ out)        // (N,N,64)
{
    const int lane = threadIdx.x & 63;
    const int waveInBlock = threadIdx.x >> 6;
    const int q = lane & 15;
    const int g = lane >> 4;
    const int d0 = q * 4;

    // Per-lane weight fragments (uniform across loop iterations).
    float w1r[4][4];   // w1r[k][m] = w1[d0+k][m]
#pragma unroll
    for (int k = 0; k < 4; ++k) {
        float4 v = *reinterpret_cast<const float4*>(w1 + (d0 + k) * 4);
        w1r[k][0] = v.x; w1r[k][1] = v.y; w1r[k][2] = v.z; w1r[k][3] = v.w;
    }
    float w2c[4][4];   // w2c[m][k] = w2[m][d0+k]
#pragma unroll
    for (int m = 0; m < 4; ++m) {
        float4 v = *reinterpret_cast<const float4*>(w2 + m * DIM + d0);
        w2c[m][0] = v.x; w2c[m][1] = v.y; w2c[m][2] = v.z; w2c[m][3] = v.w;
    }

    const unsigned totalPairs = (unsigned)NATOMS * (unsigned)NATOMS; // 4,194,304
    const unsigned wavesTotal = (unsigned)gridDim.x * (blockDim.x >> 6);
    const unsigned wid = (unsigned)blockIdx.x * (blockDim.x >> 6) + waveInBlock;

    const float PREF_NUM = 0.6324555320336759f;  // sqrt(2/5)

    for (unsigned p0 = wid * 4; p0 < totalPairs; p0 += wavesTotal * 4) {
        const unsigned p = p0 + (unsigned)g;
        const int i = (int)(p >> 11);
        const int j = (int)(p & (NATOMS - 1));

        const float ax = atoms[i * 3 + 0];
        const float ay = atoms[i * 3 + 1];
        const float az = atoms[i * 3 + 2];
        const float bx = atoms[j * 3 + 0];
        const float by = atoms[j * 3 + 1];
        const float bz = atoms[j * 3 + 2];

        const float dx = ax - bx, dy = ay - by, dz = az - bz;
        float x = __builtin_amdgcn_sqrtf(fmaf(dx, dx, fmaf(dy, dy, dz * dz)));
        x += 1e-8f;                       // x_ext, used in BOTH sin arg and divisor
        const float inv  = __builtin_amdgcn_rcpf(x);
        const float pref = PREF_NUM * inv;
        const float xr   = x * 0.1f;      // revolutions per (d+1): (d+1)*pi*x/5 rad = (d+1)*x/10 rev

        float t0 = 0.f, t1 = 0.f, t2 = 0.f, t3 = 0.f;
#pragma unroll
        for (int k = 0; k < 4; ++k) {
            float r = (float)(d0 + k + 1) * xr;
            r = r - floorf(r);                       // v_fract
            const float s = __builtin_amdgcn_sinf(r); // sin(2*pi*r)
            const float b = s * pref;
            t0 = fmaf(b, w1r[k][0], t0);
            t1 = fmaf(b, w1r[k][1], t1);
            t2 = fmaf(b, w1r[k][2], t2);
            t3 = fmaf(b, w1r[k][3], t3);
        }

        // Reduce t[0..3] across the 16 lanes of this group (xor masks < 16
        // never cross the 16-lane group boundary).
#pragma unroll
        for (int mask = 1; mask < 16; mask <<= 1) {
            t0 += __shfl_xor(t0, mask, 64);
            t1 += __shfl_xor(t1, mask, 64);
            t2 += __shfl_xor(t2, mask, 64);
            t3 += __shfl_xor(t3, mask, 64);
        }

        // Outputs o = d0..d0+3 for this lane.
        float4 o4;
        o4.x = fmaf(t0, w2c[0][0], fmaf(t1, w2c[1][0], fmaf(t2, w2c[2][0], t3 * w2c[3][0])));
        o4.y = fmaf(t0, w2c[0][1], fmaf(t1, w2c[1][1], fmaf(t2, w2c[2][1], t3 * w2c[3][1])));
        o4.z = fmaf(t0, w2c[0][2], fmaf(t1, w2c[1][2], fmaf(t2, w2c[2][2], t3 * w2c[3][2])));
        o4.w = fmaf(t0, w2c[0][3], fmaf(t1, w2c[1][3], fmaf(t2, w2c[2][3], t3 * w2c[3][3])));

        // out[p*64 + d0 .. +3] -> float4 index p*16 + q; wave stores 1 KB contiguous.
        reinterpret_cast<float4*>(out)[(size_t)p * 16 + q] = o4;
    }
}

extern "C" void kernel_launch(void* const* d_in, const int* in_sizes, int n_in,
                              void* d_out, int out_size, void* d_ws, size_t ws_size,
                              hipStream_t stream) {
    const float* atoms = (const float*)d_in[0];
    const float* w1    = (const float*)d_in[1];
    const float* w2    = (const float*)d_in[2];
    float* out         = (float*)d_out;

    // 4096 blocks x 256 threads = 16384 waves; 4 pairs/wave/iter -> 64 iters.
    dim3 grid(4096), block(256);
    hipLaunchKernelGGL(bessel_rbf_kernel, grid, block, 0, stream, atoms, w1, w2, out);
}

// Round 2
// 215.355 us; speedup vs baseline: 1.1788x; 1.1788x over previous
//
#include <hip/hip_runtime.h>
#include <math.h>

#define NATOMS 2048
#define DIM 64

// 8 lanes per pair (g = lane>>3 -> pair p0+g, 8 pairs per wave-iter).
// q = lane&7 owns basis dims d0 = q*8 .. q*8+7 (consecutive -> sin recurrence)
// and output dims {4q..4q+3} U {32+4q..32+4q+3} (so the two float4 stores are
// each contiguous 128B runs across the 8 lanes of a group).
//
// t[m] = sum_d sin((d+1)*pi*x/5) * w1[d][m], reduced over the 8 lanes (3
// shuffle rounds); out[o] = (sqrt(2/5)/x) * sum_m t[m] * w2[m][o], with
// sqrt(2/5) pre-folded into the w2 register fragments and 1/x applied once
// to t after the reduce.
__global__ __launch_bounds__(256) void bessel_rbf_kernel(
    const float* __restrict__ atoms,
    const float* __restrict__ w1,   // (64,4)
    const float* __restrict__ w2,   // (4,64)
    float* __restrict__ out)        // (N,N,64)
{
    const int lane = threadIdx.x & 63;
    const int waveInBlock = threadIdx.x >> 6;
    const int q = lane & 7;
    const int g = lane >> 3;
    const int d0 = q * 8;

    // w1 rows d0..d0+7
    float w1r[8][4];
#pragma unroll
    for (int k = 0; k < 8; ++k) {
        float4 v = *reinterpret_cast<const float4*>(w1 + (d0 + k) * 4);
        w1r[k][0] = v.x; w1r[k][1] = v.y; w1r[k][2] = v.z; w1r[k][3] = v.w;
    }

    // w2 columns 4q..4q+3 (A) and 32+4q..32+4q+3 (B), pre-scaled by sqrt(2/5)
    const float PREF = 0.6324555320336759f; // sqrt(2/5)
    float w2a[4][4], w2b[4][4];
#pragma unroll
    for (int m = 0; m < 4; ++m) {
        float4 va = *reinterpret_cast<const float4*>(w2 + m * DIM + 4 * q);
        float4 vb = *reinterpret_cast<const float4*>(w2 + m * DIM + 32 + 4 * q);
        w2a[m][0] = va.x * PREF; w2a[m][1] = va.y * PREF;
        w2a[m][2] = va.z * PREF; w2a[m][3] = va.w * PREF;
        w2b[m][0] = vb.x * PREF; w2b[m][1] = vb.y * PREF;
        w2b[m][2] = vb.z * PREF; w2b[m][3] = vb.w * PREF;
    }

    const unsigned totalPairs = (unsigned)NATOMS * (unsigned)NATOMS;
    const unsigned wavesTotal = (unsigned)gridDim.x * (blockDim.x >> 6);
    const unsigned wid = (unsigned)blockIdx.x * (blockDim.x >> 6) + waveInBlock;

    const float dk1 = (float)(d0 + 1);  // per-lane constant

    float4* __restrict__ out4 = reinterpret_cast<float4*>(out);

    for (unsigned p0 = wid * 8; p0 < totalPairs; p0 += wavesTotal * 8) {
        // 8 divides the row length, so all 8 pairs share row i (wave-uniform).
        const int i = __builtin_amdgcn_readfirstlane((int)(p0 >> 11));
        const int j = (int)(p0 & (NATOMS - 1)) + g;

        const float ax = atoms[i * 3 + 0];
        const float ay = atoms[i * 3 + 1];
        const float az = atoms[i * 3 + 2];
        const float bx = atoms[j * 3 + 0];
        const float by = atoms[j * 3 + 1];
        const float bz = atoms[j * 3 + 2];

        const float dx = ax - bx, dy = ay - by, dz = az - bz;
        float x = __builtin_amdgcn_sqrtf(fmaf(dx, dx, fmaf(dy, dy, dz * dz)));
        x += 1e-8f;                              // x_ext (sin arg AND divisor)
        const float inv = __builtin_amdgcn_rcpf(x);
        const float xr  = x * 0.1f;              // step angle in revolutions

        // sin((d0+k+1)*2*pi*xr) via Chebyshev: s_{k+1} = 2c*s_k - s_{k-1}
        float r0 = dk1 * xr;
        float r1 = r0 + xr;
        r0 = r0 - floorf(r0);
        r1 = r1 - floorf(r1);
        float rc = xr - floorf(xr);
        const float a0   = __builtin_amdgcn_sinf(r0);
        const float a1   = __builtin_amdgcn_sinf(r1);
        const float c1   = __builtin_amdgcn_cosf(rc);
        const float twoC = c1 + c1;

        float t[4];
#pragma unroll
        for (int m = 0; m < 4; ++m)
            t[m] = fmaf(a1, w1r[1][m], a0 * w1r[0][m]);
        float sp = a0, sc = a1;
#pragma unroll
        for (int k = 2; k < 8; ++k) {
            const float sn = fmaf(twoC, sc, -sp);
#pragma unroll
            for (int m = 0; m < 4; ++m)
                t[m] = fmaf(sn, w1r[k][m], t[m]);
            sp = sc; sc = sn;
        }

        // Reduce across the 8 lanes of this group (masks < 8 stay in-group).
#pragma unroll
        for (int mask = 1; mask < 8; mask <<= 1) {
            t[0] += __shfl_xor(t[0], mask, 64);
            t[1] += __shfl_xor(t[1], mask, 64);
            t[2] += __shfl_xor(t[2], mask, 64);
            t[3] += __shfl_xor(t[3], mask, 64);
        }
        t[0] *= inv; t[1] *= inv; t[2] *= inv; t[3] *= inv;

        // Project to this lane's 8 outputs.
        float4 oA, oB;
        oA.x = fmaf(t[0], w2a[0][0], fmaf(t[1], w2a[1][0], fmaf(t[2], w2a[2][0], t[3] * w2a[3][0])));
        oA.y = fmaf(t[0], w2a[0][1], fmaf(t[1], w2a[1][1], fmaf(t[2], w2a[2][1], t[3] * w2a[3][1])));
        oA.z = fmaf(t[0], w2a[0][2], fmaf(t[1], w2a[1][2], fmaf(t[2], w2a[2][2], t[3] * w2a[3][2])));
        oA.w = fmaf(t[0], w2a[0][3], fmaf(t[1], w2a[1][3], fmaf(t[2], w2a[2][3], t[3] * w2a[3][3])));
        oB.x = fmaf(t[0], w2b[0][0], fmaf(t[1], w2b[1][0], fmaf(t[2], w2b[2][0], t[3] * w2b[3][0])));
        oB.y = fmaf(t[0], w2b[0][1], fmaf(t[1], w2b[1][1], fmaf(t[2], w2b[2][1], t[3] * w2b[3][1])));
        oB.z = fmaf(t[0], w2b[0][2], fmaf(t[1], w2b[1][2], fmaf(t[2], w2b[2][2], t[3] * w2b[3][2])));
        oB.w = fmaf(t[0], w2b[0][3], fmaf(t[1], w2b[1][3], fmaf(t[2], w2b[2][3], t[3] * w2b[3][3])));

        // Pair region = 256B = 16 float4s; store [0,128) and [128,256) halves.
        const size_t base = (size_t)(p0 + (unsigned)g) * 16;
        out4[base + q]     = oA;
        out4[base + 8 + q] = oB;
    }
}

extern "C" void kernel_launch(void* const* d_in, const int* in_sizes, int n_in,
                              void* d_out, int out_size, void* d_ws, size_t ws_size,
                              hipStream_t stream) {
    const float* atoms = (const float*)d_in[0];
    const float* w1    = (const float*)d_in[1];
    const float* w2    = (const float*)d_in[2];
    float* out         = (float*)d_out;

    // 2048 blocks x 256 threads = 8192 waves; 8 pairs/wave/iter -> 64 iters.
    dim3 grid(2048), block(256);
    hipLaunchKernelGGL(bessel_rbf_kernel, grid, block, 0, stream, atoms, w1, w2, out);
}